// Round 8
// baseline (154.788 us; speedup 1.0000x reference)
//
#include <hip/hip_runtime.h>

// B=16, S=256, IN=128, OUT=128, HID=512
// y[b,o] = sum_k M[b,k]*W2f[k*128+o] + sum_i sx[b,i]*b2[i*128+o];  out = y@Wfc + bfc
//   M[b,h,i] = sum_s h[b,s,h]*x[b,s,i],  h = relu(x@W1+b1)  (h kept in LDS, never stored)
//
// ONE persistent kernel, 256 blocks x 256 threads (1 block/CU, co-resident),
// software grid barriers between phases. Phases:
//   AB: block=(b, h0 of 8 x64hid, sh of 2 s-halves): GEMM1 (x@W1c -> ht in LDS),
//       GEMM2 (Mp[sh] += ht^T @ x), fused sx column sums (h0==0 blocks).
//   C : 512 hid-chunks (2 per block): part[c] = Ms(c) @ W2-rows(c)
//   D1: reduce part[512] -> part2[32]
//   D2: blocks<16: reduce part2, b2 term, Wfc, bfc -> out

#define NB 256

// ws float offsets
#define OFF_MP    0          // Mp   [2][16][65536] = 2097152 floats
#define OFF_PART  2097152    // part [512][16][128] = 1048576
#define OFF_PART2 3145728    // part2[32][16][128]  = 65536
#define OFF_SXP   3211264    // sxp  [2][16][128]   = 4096
#define OFF_CNT   3215360    // 3 ints (barrier counters), memset to 0 each call

__device__ __forceinline__ void grid_barrier(int* cnt, int phase) {
    __syncthreads();
    if (threadIdx.x == 0) {
        __threadfence();
        __hip_atomic_fetch_add(&cnt[phase], 1, __ATOMIC_ACQ_REL, __HIP_MEMORY_SCOPE_AGENT);
        long spins = 0;
        while (__hip_atomic_load(&cnt[phase], __ATOMIC_ACQUIRE, __HIP_MEMORY_SCOPE_AGENT) < NB) {
            __builtin_amdgcn_s_sleep(2);
            if (++spins > (1L << 27)) break;   // deadlock insurance; never triggers when co-resident
        }
        __threadfence();
    }
    __syncthreads();
}

__global__ __launch_bounds__(256) void k_fused(
        const float* __restrict__ x,  const float* __restrict__ W1,
        const float* __restrict__ b1, const float* __restrict__ W2,
        const float* __restrict__ b2, const float* __restrict__ Wfc,
        const float* __restrict__ bfc, float* __restrict__ ws,
        float* __restrict__ out) {
    __shared__ float W1c[128][64];   // 32 KB
    __shared__ float xs[64][132];    // 33.8 KB (pad 4: float4-aligned rows, conflict-free reads)
    __shared__ float ht[64][68];     // 17.4 KB
    __shared__ float b1c[64];
    __shared__ float Ms[16][128];    // 8 KB (phase C)
    __shared__ float sxs[128];       // phase D2
    __shared__ float ysh[128];
    __shared__ float shd[2][128];

    float* Mp    = ws + OFF_MP;
    float* part  = ws + OFF_PART;
    float* part2 = ws + OFF_PART2;
    float* sxp   = ws + OFF_SXP;
    int*   cnt   = (int*)(ws + OFF_CNT);

    const int tid = threadIdx.x;
    const int blk = blockIdx.x;
    const int ty = tid >> 4, tx = tid & 15;

    // ---------------- Phase AB ----------------
    {
        const int b  = blk >> 4;
        const int h0 = (blk >> 1) & 7;   // hid chunk *64
        const int sh = blk & 1;          // s-half of 128
        {
            const int r = tid >> 4, c4 = (tid & 15) * 4;
            #pragma unroll
            for (int p = 0; p < 8; ++p) {
                const int k = p * 16 + r;
                *(float4*)&W1c[k][c4] = *(const float4*)&W1[(size_t)k * 512 + h0 * 64 + c4];
            }
            if (tid < 64) b1c[tid] = b1[h0 * 64 + tid];
        }
        float Macc[4][8] = {};
        float sxacc = 0.f;
        for (int st = 0; st < 2; ++st) {
            const int s_base = sh * 128 + st * 64;
            __syncthreads();
            #pragma unroll
            for (int p = 0; p < 8; ++p) {
                const int f4 = p * 256 + tid;
                const int row = f4 >> 5, c4 = (f4 & 31) * 4;
                *(float4*)&xs[row][c4] = *(const float4*)&x[(size_t)(b * 256 + s_base + row) * 128 + c4];
            }
            __syncthreads();
            // GEMM1: ht[64 tok][64 hid] = relu(xs @ W1c + b1c)
            float a1[4][4] = {};
            #pragma unroll 4
            for (int k = 0; k < 128; ++k) {
                float av[4];
                #pragma unroll
                for (int i = 0; i < 4; ++i) av[i] = xs[ty * 4 + i][k];
                const float4 w = *(const float4*)&W1c[k][tx * 4];
                const float wv[4] = {w.x, w.y, w.z, w.w};
                #pragma unroll
                for (int i = 0; i < 4; ++i)
                    #pragma unroll
                    for (int j = 0; j < 4; ++j)
                        a1[i][j] += av[i] * wv[j];
            }
            #pragma unroll
            for (int i = 0; i < 4; ++i) {
                float4 v; float* vp = (float*)&v;
                #pragma unroll
                for (int j = 0; j < 4; ++j) {
                    const float tv = a1[i][j] + b1c[tx * 4 + j];
                    vp[j] = tv > 0.f ? tv : 0.f;
                }
                *(float4*)&ht[ty * 4 + i][tx * 4] = v;
            }
            __syncthreads();
            // GEMM2: Macc[hid 4][in 8] += ht^T @ xs   (in = tx*4..+4 and 64+tx*4..+4)
            #pragma unroll 4
            for (int s2 = 0; s2 < 64; ++s2) {
                const float4 hh = *(const float4*)&ht[s2][ty * 4];
                const float4 xa = *(const float4*)&xs[s2][tx * 4];
                const float4 xb = *(const float4*)&xs[s2][64 + tx * 4];
                const float hv[4] = {hh.x, hh.y, hh.z, hh.w};
                const float xv[8] = {xa.x, xa.y, xa.z, xa.w, xb.x, xb.y, xb.z, xb.w};
                #pragma unroll
                for (int i = 0; i < 4; ++i)
                    #pragma unroll
                    for (int j = 0; j < 8; ++j)
                        Macc[i][j] += hv[i] * xv[j];
            }
            // fused sx partial (column sums of xs), only h0==0 blocks
            if (h0 == 0 && tid < 128) {
                #pragma unroll 16
                for (int s2 = 0; s2 < 64; ++s2) sxacc += xs[s2][tid];
            }
        }
        if (h0 == 0 && tid < 128)
            sxp[sh * 2048 + b * 128 + tid] = sxacc;
        const size_t mpbase = (size_t)sh * (16 * 65536) + (size_t)b * 65536;
        #pragma unroll
        for (int i = 0; i < 4; ++i) {
            const int hid = h0 * 64 + ty * 4 + i;
            float4 v0 = {Macc[i][0], Macc[i][1], Macc[i][2], Macc[i][3]};
            float4 v1 = {Macc[i][4], Macc[i][5], Macc[i][6], Macc[i][7]};
            *(float4*)&Mp[mpbase + (size_t)hid * 128 + tx * 4] = v0;
            *(float4*)&Mp[mpbase + (size_t)hid * 128 + 64 + tx * 4] = v1;
        }
    }
    grid_barrier(cnt, 0);

    // ---------------- Phase C: part[c] = Ms(c) @ W2-rows(c), c = hid 0..511 ----------------
    {
        const int o = tid & 127, half = tid >> 7;
        for (int q = 0; q < 2; ++q) {
            const int c = blk * 2 + q;
            __syncthreads();
            #pragma unroll
            for (int p = 0; p < 8; ++p) {
                const int flat = p * 256 + tid;
                const int bb = flat >> 7, ii = flat & 127;
                Ms[bb][ii] = Mp[(size_t)bb * 65536 + c * 128 + ii]
                           + Mp[(size_t)(16 + bb) * 65536 + c * 128 + ii];
            }
            __syncthreads();
            float acc[8] = {};
            #pragma unroll 2
            for (int k4 = 0; k4 < 32; ++k4) {
                const size_t wb = (size_t)(c * 128 + k4 * 4) * 128 + o;
                const float w0 = W2[wb];
                const float w1 = W2[wb + 128];
                const float w2 = W2[wb + 256];
                const float w3 = W2[wb + 384];
                #pragma unroll
                for (int j = 0; j < 8; ++j) {
                    const float4 m = *(const float4*)&Ms[half * 8 + j][k4 * 4];
                    acc[j] += m.x * w0 + m.y * w1 + m.z * w2 + m.w * w3;
                }
            }
            #pragma unroll
            for (int j = 0; j < 8; ++j)
                part[(size_t)(c * 16 + half * 8 + j) * 128 + o] = acc[j];
        }
    }
    grid_barrier(cnt, 1);

    // ---------------- Phase D1: part[512] -> part2[32] ----------------
    {
        const int b = blk & 15, pg = blk >> 4;
        const int o = tid & 127, half = tid >> 7;
        const int r = pg * 2 + half;             // 0..31
        float acc = 0.f;
        #pragma unroll
        for (int j = 0; j < 16; ++j)
            acc += part[(size_t)((r * 16 + j) * 16 + b) * 128 + o];
        part2[(size_t)(r * 16 + b) * 128 + o] = acc;
    }
    grid_barrier(cnt, 2);

    // ---------------- Phase D2: final (blocks 0..15) ----------------
    if (blk < 16) {
        const int b = blk;
        const int o = tid & 127, g = tid >> 7;   // 2 groups
        float y = 0.f;
        #pragma unroll
        for (int pp = g * 16; pp < g * 16 + 16; ++pp)
            y += part2[(size_t)(pp * 16 + b) * 128 + o];
        if (g == 0) sxs[o] = sxp[b * 128 + o] + sxp[2048 + b * 128 + o];
        __syncthreads();
        #pragma unroll 4
        for (int i = g * 64; i < g * 64 + 64; ++i)
            y += sxs[i] * b2[i * 128 + o];
        shd[g][o] = y;
        __syncthreads();
        if (g == 0) ysh[o] = shd[0][o] + shd[1][o];
        __syncthreads();
        float f = 0.f;
        #pragma unroll 4
        for (int oo = g * 64; oo < g * 64 + 64; ++oo)
            f += ysh[oo] * Wfc[oo * 128 + o];
        shd[g][o] = f;
        __syncthreads();
        if (g == 0)
            out[b * 128 + o] = bfc[o] + shd[0][o] + shd[1][o];
    }
}

extern "C" void kernel_launch(void* const* d_in, const int* in_sizes, int n_in,
                              void* d_out, int out_size, void* d_ws, size_t ws_size,
                              hipStream_t stream) {
    const float* x   = (const float*)d_in[0];
    const float* W1  = (const float*)d_in[1];
    const float* b1  = (const float*)d_in[2];
    const float* W2  = (const float*)d_in[3];
    const float* b2  = (const float*)d_in[4];
    const float* Wfc = (const float*)d_in[5];
    const float* bfc = (const float*)d_in[6];
    float* ws  = (float*)d_ws;
    float* out = (float*)d_out;

    // zero the 3 barrier counters (ws is NOT re-poisoned between replays, but
    // counters must start at 0 every call -> tiny memset node each launch)
    hipMemsetAsync((char*)d_ws + (size_t)OFF_CNT * 4, 0, 12, stream);
    k_fused<<<NB, 256, 0, stream>>>(x, W1, b1, W2, b2, Wfc, bfc, ws, out);
}

// Round 9
// 45.689 us; speedup vs baseline: 3.3879x; 3.3879x over previous
//
#include <hip/hip_runtime.h>

// B=16, S=256, IN=128, OUT=128, HID=512
// y[b,o] = sum_{k=h*128+i} M[b,k]*W2f[k*128+o] + sum_i sx[b,i]*b2[i*128+o]
//   M[b,h,i] = sum_s h[b,s,h]*x[b,s,i],  h = relu(x@W1+b1);  out = y@Wfc + bfc
// Stages A (h) and B (M) in bf16 MFMA (f32 accum); C/D f32 (R3-proven).

typedef __attribute__((ext_vector_type(8))) short     s16x8;
typedef __attribute__((ext_vector_type(8))) unsigned short u16x8;
typedef __attribute__((ext_vector_type(4))) float     f32x4;

__device__ __forceinline__ unsigned short f2bf(float f) {
    union { float f; unsigned int u; } v; v.f = f;
    unsigned int r = v.u + 0x7FFFu + ((v.u >> 16) & 1u);   // RNE
    return (unsigned short)(r >> 16);
}

// ws float offsets
#define OFF_XB   0          // xb   bf16 [16][256][128] -> 262144 f
#define OFF_XT   262144     // xT   bf16 [16][128][256] -> 262144 f
#define OFF_W1T  524288     // W1T  bf16 [512][128]     -> 32768 f
#define OFF_HT   557056     // hT   bf16 [16][512][256] -> 1048576 f
#define OFF_M    1605632    // M    f32  [16][65536]    -> 1048576 f
#define OFF_PART 2654208    // part f32  [512][16][128] -> 1048576 f
#define OFF_Y1   3702784    // y1   f32  [16][16][128]  -> 32768 f
#define OFF_SXP  3735552    // sxp  f32  [4][16][128]   -> 8192 f

// ---------- prep: bf16 copies (xb row-major, xT/W1T K-major) + sx partials ----------
__global__ __launch_bounds__(256) void k_prep(const float* __restrict__ x,
        const float* __restrict__ W1, unsigned short* __restrict__ xb,
        unsigned short* __restrict__ xT, unsigned short* __restrict__ W1T,
        float* __restrict__ sxp) {
    const int tid = threadIdx.x;
    const int blk = blockIdx.x;
    if (blk < 64) {
        __shared__ float xs[64][132];
        const int b = blk >> 2, sg = blk & 3;
        #pragma unroll
        for (int p = 0; p < 8; ++p) {
            const int f4 = p * 256 + tid;
            const int r = f4 >> 5, c4 = (f4 & 31) * 4;
            *(float4*)&xs[r][c4] = *(const float4*)&x[(size_t)(b * 256 + sg * 64 + r) * 128 + c4];
        }
        __syncthreads();
        {   // xb: row-major bf16
            const int r = tid >> 2, q = tid & 3;
            unsigned short tmp[32] __attribute__((aligned(16)));
            #pragma unroll
            for (int m = 0; m < 32; ++m) tmp[m] = f2bf(xs[r][q * 32 + m]);
            #pragma unroll
            for (int v = 0; v < 4; ++v)
                *(u16x8*)&xb[(size_t)(b * 256 + sg * 64 + r) * 128 + q * 32 + v * 8] =
                    *(u16x8*)&tmp[v * 8];
        }
        {   // xT: [i][s] bf16
            const int i = tid >> 1, qq = tid & 1;
            unsigned short tmp[32] __attribute__((aligned(16)));
            #pragma unroll
            for (int m = 0; m < 32; ++m) tmp[m] = f2bf(xs[qq * 32 + m][i]);
            #pragma unroll
            for (int v = 0; v < 4; ++v)
                *(u16x8*)&xT[(size_t)(b * 128 + i) * 256 + sg * 64 + qq * 32 + v * 8] =
                    *(u16x8*)&tmp[v * 8];
        }
        if (tid < 128) {   // sx partial over this 64-s chunk
            float acc = 0.f;
            #pragma unroll 16
            for (int s = 0; s < 64; ++s) acc += xs[s][tid];
            sxp[(size_t)(sg * 16 + b) * 128 + tid] = acc;
        }
    } else {
        // W1T[h][i] bf16 from W1[i][h]; blocks 64..79, 32 h-rows each
        const int w = blk - 64;
        const int hh = tid >> 3, ii = tid & 7;
        const int h = w * 32 + hh;
        unsigned short tmp[16] __attribute__((aligned(16)));
        #pragma unroll
        for (int m = 0; m < 16; ++m)
            tmp[m] = f2bf(W1[(size_t)(ii * 16 + m) * 512 + h]);
        *(u16x8*)&W1T[(size_t)h * 128 + ii * 16]     = *(u16x8*)&tmp[0];
        *(u16x8*)&W1T[(size_t)h * 128 + ii * 16 + 8] = *(u16x8*)&tmp[8];
    }
}

// ---------- Stage A (MFMA): hT[b][hid][s] = relu(x@W1+b1)^T in bf16 ----------
__global__ __launch_bounds__(256) void k_hyp1m(const unsigned short* __restrict__ xb,
        const unsigned short* __restrict__ W1T, const float* __restrict__ b1,
        unsigned short* __restrict__ hT) {
    __shared__ unsigned short smem[2 * 128 * 136];   // xA | Ws ; hts aliases xA
    unsigned short (*xA)[136] = (unsigned short(*)[136])smem;
    unsigned short (*Ws)[136] = (unsigned short(*)[136])(smem + 128 * 136);
    __shared__ float b1s[128];
    const int tid = threadIdx.x;
    const int tb = blockIdx.x >> 2, hb = blockIdx.x & 3;  // tok-tile 128, hid-tile 128
    const int b = tb >> 1, s0 = (tb & 1) * 128;
    {
        const int r = tid >> 1, q = tid & 1;
        #pragma unroll
        for (int m = 0; m < 8; ++m) {
            *(u16x8*)&xA[r][q * 64 + m * 8] =
                *(const u16x8*)&xb[(size_t)(b * 256 + s0 + r) * 128 + q * 64 + m * 8];
            *(u16x8*)&Ws[r][q * 64 + m * 8] =
                *(const u16x8*)&W1T[(size_t)(hb * 128 + r) * 128 + q * 64 + m * 8];
        }
        if (tid < 128) b1s[tid] = b1[hb * 128 + tid];
    }
    __syncthreads();
    const int w = tid >> 6, lane = tid & 63;
    const int wr = w >> 1, wc = w & 1;
    const int l15 = lane & 15, kl = lane >> 4;
    f32x4 zero = {0.f, 0.f, 0.f, 0.f};
    f32x4 acc[4][4];
    #pragma unroll
    for (int i = 0; i < 4; ++i)
        #pragma unroll
        for (int j = 0; j < 4; ++j) acc[i][j] = zero;
    #pragma unroll
    for (int ks = 0; ks < 4; ++ks) {
        s16x8 a[4], bb[4];
        #pragma unroll
        for (int f = 0; f < 4; ++f) {
            a[f]  = *(const s16x8*)&xA[wr * 64 + f * 16 + l15][ks * 32 + kl * 8];
            bb[f] = *(const s16x8*)&Ws[wc * 64 + f * 16 + l15][ks * 32 + kl * 8];
        }
        #pragma unroll
        for (int fr = 0; fr < 4; ++fr)
            #pragma unroll
            for (int fc = 0; fc < 4; ++fc)
                acc[fr][fc] = __builtin_amdgcn_mfma_f32_16x16x32_bf16(a[fr], bb[fc], acc[fr][fc], 0, 0, 0);
    }
    __syncthreads();   // xA dead; alias as hts[128 hid][136 s]
    unsigned short (*hts)[136] = (unsigned short(*)[136])smem;
    #pragma unroll
    for (int fr = 0; fr < 4; ++fr)
        #pragma unroll
        for (int fc = 0; fc < 4; ++fc)
            #pragma unroll
            for (int j = 0; j < 4; ++j) {
                const int tok = wr * 64 + fr * 16 + kl * 4 + j;   // C row
                const int hid = wc * 64 + fc * 16 + l15;          // C col
                float v = acc[fr][fc][j] + b1s[hid];
                hts[hid][tok] = f2bf(v > 0.f ? v : 0.f);
            }
    __syncthreads();
    {
        const int r = tid >> 1, q = tid & 1;
        #pragma unroll
        for (int m = 0; m < 8; ++m)
            *(u16x8*)&hT[(size_t)(b * 512 + hb * 128 + r) * 256 + s0 + q * 64 + m * 8] =
                *(u16x8*)&hts[r][q * 64 + m * 8];
    }
}

// ---------- Stage B (MFMA): M[b][h][i] = sum_s hT[h][s]*xT[i][s], f32 out ----------
__global__ __launch_bounds__(256) void k_hyp2m(const unsigned short* __restrict__ hT,
        const unsigned short* __restrict__ xT, float* __restrict__ M) {
    __shared__ unsigned short hs[128][72];
    __shared__ unsigned short xs[128][72];
    const int tid = threadIdx.x;
    const int b = blockIdx.x >> 2, hb = blockIdx.x & 3;   // h-tile 128, i full 128
    const int w = tid >> 6, lane = tid & 63;
    const int wr = w >> 1, wc = w & 1;
    const int l15 = lane & 15, kl = lane >> 4;
    f32x4 zero = {0.f, 0.f, 0.f, 0.f};
    f32x4 acc[4][4];
    #pragma unroll
    for (int i = 0; i < 4; ++i)
        #pragma unroll
        for (int j = 0; j < 4; ++j) acc[i][j] = zero;
    for (int sc = 0; sc < 4; ++sc) {
        __syncthreads();
        {
            const int r = tid >> 1, q = tid & 1;
            #pragma unroll
            for (int m = 0; m < 4; ++m) {
                *(u16x8*)&hs[r][q * 32 + m * 8] =
                    *(const u16x8*)&hT[(size_t)(b * 512 + hb * 128 + r) * 256 + sc * 64 + q * 32 + m * 8];
                *(u16x8*)&xs[r][q * 32 + m * 8] =
                    *(const u16x8*)&xT[(size_t)(b * 128 + r) * 256 + sc * 64 + q * 32 + m * 8];
            }
        }
        __syncthreads();
        #pragma unroll
        for (int ki = 0; ki < 2; ++ki) {
            s16x8 a[4], bb[4];
            #pragma unroll
            for (int f = 0; f < 4; ++f) {
                a[f]  = *(const s16x8*)&hs[wr * 64 + f * 16 + l15][ki * 32 + kl * 8];
                bb[f] = *(const s16x8*)&xs[wc * 64 + f * 16 + l15][ki * 32 + kl * 8];
            }
            #pragma unroll
            for (int fr = 0; fr < 4; ++fr)
                #pragma unroll
                for (int fc = 0; fc < 4; ++fc)
                    acc[fr][fc] = __builtin_amdgcn_mfma_f32_16x16x32_bf16(a[fr], bb[fc], acc[fr][fc], 0, 0, 0);
        }
    }
    #pragma unroll
    for (int fr = 0; fr < 4; ++fr)
        #pragma unroll
        for (int fc = 0; fc < 4; ++fc)
            #pragma unroll
            for (int j = 0; j < 4; ++j) {
                const int h = hb * 128 + wr * 64 + fr * 16 + kl * 4 + j;
                const int i = wc * 64 + fc * 16 + l15;
                M[(size_t)b * 65536 + (size_t)h * 128 + i] = acc[fr][fc][j];
            }
}

// ---------- Stage C: split-K partials of y = M @ W2flat (K=128/block) ----------
__global__ __launch_bounds__(256) void k_hyp3(const float* __restrict__ M,
        const float* __restrict__ W2, float* __restrict__ part) {
    __shared__ float Ms[16][128];
    const int tid = threadIdx.x;
    const int p = blockIdx.x;
    const int k0 = p * 128;
    #pragma unroll
    for (int r = 0; r < 8; ++r) {
        const int flat = r * 256 + tid;
        const int b = flat >> 7, kk = flat & 127;
        Ms[b][kk] = M[(size_t)b * 65536 + k0 + kk];
    }
    __syncthreads();
    const int o = tid & 127, half = tid >> 7;
    float acc[8] = {};
    #pragma unroll 4
    for (int kk = 0; kk < 128; ++kk) {
        const float w = W2[(size_t)(k0 + kk) * 128 + o];
        #pragma unroll
        for (int j = 0; j < 8; ++j)
            acc[j] += Ms[half * 8 + j][kk] * w;
    }
    #pragma unroll
    for (int j = 0; j < 8; ++j)
        part[(size_t)(p * 16 + half * 8 + j) * 128 + o] = acc[j];
}

// ---------- D1: tree-reduce part[512] -> y1[16][16][128] ----------
__global__ __launch_bounds__(128) void k_red(const float* __restrict__ part,
        float* __restrict__ y1) {
    const int b  = blockIdx.x & 15;
    const int pg = blockIdx.x >> 4;
    const int t  = threadIdx.x;
    float acc = 0.f;
    #pragma unroll
    for (int pp = 0; pp < 32; ++pp)
        acc += part[(size_t)((pg * 32 + pp) * 16 + b) * 128 + t];
    y1[(size_t)(pg * 16 + b) * 128 + t] = acc;
}

// ---------- D2: final reduce + b2 term + Wfc + bfc ----------
__global__ __launch_bounds__(512) void k_hyp4(const float* __restrict__ y1,
        const float* __restrict__ sxp, const float* __restrict__ b2,
        const float* __restrict__ Wfc, const float* __restrict__ bfc,
        float* __restrict__ out) {
    __shared__ float sh[4][128];
    __shared__ float sxs[128];
    __shared__ float ysh[128];
    const int b = blockIdx.x;
    const int t = threadIdx.x & 127;
    const int g = threadIdx.x >> 7;
    float y = 0.f;
    #pragma unroll
    for (int pg = g * 4; pg < g * 4 + 4; ++pg)
        y += y1[(size_t)(pg * 16 + b) * 128 + t];
    sh[g][t] = sxp[(size_t)(g * 16 + b) * 128 + t];   // 4 sx chunks, one per group
    __syncthreads();
    if (g == 0) sxs[t] = sh[0][t] + sh[1][t] + sh[2][t] + sh[3][t];
    __syncthreads();
    #pragma unroll 8
    for (int i = g * 32; i < g * 32 + 32; ++i)
        y += sxs[i] * b2[i * 128 + t];
    sh[g][t] = y;
    __syncthreads();
    if (g == 0) ysh[t] = sh[0][t] + sh[1][t] + sh[2][t] + sh[3][t];
    __syncthreads();
    float o = 0.f;
    #pragma unroll 8
    for (int oo = g * 32; oo < g * 32 + 32; ++oo)
        o += ysh[oo] * Wfc[oo * 128 + t];
    sh[g][t] = o;
    __syncthreads();
    if (g == 0)
        out[b * 128 + t] = bfc[t] + sh[0][t] + sh[1][t] + sh[2][t] + sh[3][t];
}

extern "C" void kernel_launch(void* const* d_in, const int* in_sizes, int n_in,
                              void* d_out, int out_size, void* d_ws, size_t ws_size,
                              hipStream_t stream) {
    const float* x   = (const float*)d_in[0];
    const float* W1  = (const float*)d_in[1];
    const float* b1  = (const float*)d_in[2];
    const float* W2  = (const float*)d_in[3];
    const float* b2  = (const float*)d_in[4];
    const float* Wfc = (const float*)d_in[5];
    const float* bfc = (const float*)d_in[6];
    float* ws  = (float*)d_ws;
    unsigned short* xb  = (unsigned short*)(ws + OFF_XB);
    unsigned short* xT  = (unsigned short*)(ws + OFF_XT);
    unsigned short* W1T = (unsigned short*)(ws + OFF_W1T);
    unsigned short* hT  = (unsigned short*)(ws + OFF_HT);
    float* M    = ws + OFF_M;
    float* part = ws + OFF_PART;
    float* y1   = ws + OFF_Y1;
    float* sxp  = ws + OFF_SXP;
    float* out  = (float*)d_out;

    k_prep <<<80,  256, 0, stream>>>(x, W1, xb, xT, W1T, sxp);
    k_hyp1m<<<128, 256, 0, stream>>>(xb, W1T, b1, hT);
    k_hyp2m<<<64,  256, 0, stream>>>(hT, xT, M);
    k_hyp3 <<<512, 256, 0, stream>>>(M, W2, part);
    k_red  <<<256, 128, 0, stream>>>(part, y1);
    k_hyp4 <<<16,  512, 0, stream>>>(y1, sxp, b2, Wfc, bfc, out);
}